// Round 10
// baseline (206.047 us; speedup 1.0000x reference)
//
#include <hip/hip_runtime.h>

// Hex conv:  y[h,w,f] = relu( bias[f] + sum_taps x[h+dr, w+dc, c] * K[kr,kc][c][f] )
// parity p = h&1:
//   p==0 (7 taps): (dr,dc,kr,kc) = (0,0,0,1)(0,1,0,2)(1,-1,1,0)(1,0,1,1)(1,1,1,2)(2,0,2,1)(2,1,2,2)
//   p==1 (4 taps): (0,-1,0,1)(0,0,0,2)(1,-1,2,1)(1,0,2,2)  -> weight tiles {0,1,5,6}
// x: (16,128,128,128) fp32 NHWC; K: (3,3,128,256) fp32 HWIO; bias: (256,) fp32.
// out: (16,128,128,256) fp32.
//
// Round 10: BN 128->256 merge. 512 thr / 8 waves (2w x 4f), wave tile 64x64
// (identical per-wave shape/reads as r9), BK=64, LDS A 16KB @0 + B 32KB @16384.
// Staged via global_load_lds w=16 from pre-swizzled bf16 sources in d_ws.

#define N_  16
#define H_  128
#define W_  128
#define C_  128
#define F_  256
#define HP  130
#define WP  130

typedef short bf16x8 __attribute__((ext_vector_type(8)));  // 8 bf16 in 4 VGPRs
typedef float f32x4  __attribute__((ext_vector_type(4)));

__device__ __forceinline__ unsigned int bf_bits(float f) {
  unsigned int u = __float_as_uint(f);
  return (u + 0x7FFFu + ((u >> 16) & 1u)) >> 16;   // RNE fp32 -> bf16
}
__device__ __forceinline__ unsigned int pack2(float a, float b) {
  return bf_bits(a) | (bf_bits(b) << 16);
}

__device__ __forceinline__ void even_tap(int ti, int& dr, int& dc, int& kr, int& kc) {
  switch (ti) {
    case 0:  dr = 0; dc = 0;  kr = 0; kc = 1; break;
    case 1:  dr = 0; dc = 1;  kr = 0; kc = 2; break;
    case 2:  dr = 1; dc = -1; kr = 1; kc = 0; break;
    case 3:  dr = 1; dc = 0;  kr = 1; kc = 1; break;
    case 4:  dr = 1; dc = 1;  kr = 1; kc = 2; break;
    case 5:  dr = 2; dc = 0;  kr = 2; kc = 1; break;
    default: dr = 2; dc = 1;  kr = 2; kc = 2; break;
  }
}

// ---------- prep 1: pad + bf16-convert x, slot-swizzled by (column&7) ----------
// xpad pixel (n,hh,wp): 256B = [hc=0:128B][hc=1:128B]; each 128B = 8 slots of 16B.
// stored slot g holds channels ((g ^ ((wp-1)&7)) * 8 .. +8) + hc*64.
__global__ __launch_bounds__(256) void prep_xpad(
    const float* __restrict__ x, char* __restrict__ xpad) {
  long id = (long)blockIdx.x * 256 + threadIdx.x;     // 16B chunk id
  const long total = (long)N_ * HP * WP * 16;
  if (id >= total) return;
  const int g  = (int)(id & 7);
  const int hc = (int)((id >> 3) & 1);
  long pix = id >> 4;
  const int wp = (int)(pix % WP);
  long t = pix / WP;
  const int hh = (int)(t % HP);
  const int nn = (int)(t / HP);
  const int ww = wp - 1;
  const int key = ww & 7;
  uint4 o = make_uint4(0u, 0u, 0u, 0u);
  if (hh < H_ && ww >= 0 && ww < W_) {
    const float* s = x + (((long)(nn * H_ + hh) * W_ + ww) * C_ + hc * 64 + (g ^ key) * 8);
    float4 a = *(const float4*)s;
    float4 b = *(const float4*)(s + 4);
    o.x = pack2(a.x, a.y); o.y = pack2(a.z, a.w);
    o.z = pack2(b.x, b.y); o.w = pack2(b.z, b.w);
  }
  *(uint4*)(xpad + id * 16) = o;
}

// ---------- prep 2: weight tiles, slot-swizzled by (f&7) ----------
// wt2[ti 0..6][hc 0..1][ft 0..1] = 16KB tile: [f 0..127][slot 0..7][16B]
// stored slot g holds channels ((g ^ (f&7))*8 .. +8) + hc*64 of kernel[kr][kc][:][ft*128+f]
// For fixed (ti,hc) the two ft tiles are contiguous -> one 32KB B block.
__global__ __launch_bounds__(256) void prep_wt2(
    const float* __restrict__ k, char* __restrict__ wt2) {
  int id = blockIdx.x * 256 + threadIdx.x;            // 16B chunk id
  if (id >= 7 * 2 * 2 * 128 * 8) return;
  const int g  = id & 7;
  const int f  = (id >> 3) & 127;
  const int ft = (id >> 10) & 1;
  const int hc = (id >> 11) & 1;
  const int ti = id >> 12;
  int dr, dc, kr, kc;
  even_tap(ti, dr, dc, kr, kc);
  const int fg = ft * 128 + f;
  const int c0 = hc * 64 + (g ^ (f & 7)) * 8;
  float v[8];
#pragma unroll
  for (int j = 0; j < 8; ++j)
    v[j] = k[((size_t)(kr * 3 + kc) * C_ + (c0 + j)) * F_ + fg];
  uint4 o;
  o.x = pack2(v[0], v[1]); o.y = pack2(v[2], v[3]);
  o.z = pack2(v[4], v[5]); o.w = pack2(v[6], v[7]);
  *(uint4*)(wt2 + (size_t)id * 16) = o;
}

// ---------- main: implicit GEMM, 128(w) x 256(f) tile, 8 waves ----------
__global__ __launch_bounds__(512, 2) void hconv_mfma(
    const char* __restrict__ xpad,
    const char* __restrict__ wt2,
    const float* __restrict__ bias,
    float* __restrict__ out) {
  __shared__ __align__(16) char smem[49152];   // A 16KB @0, B 32KB @16384

  const int tid = threadIdx.x;
  // XCD-aware bijective swizzle: grid 2048 = 8 * 256
  const int bid = (blockIdx.x & 7) * 256 + (blockIdx.x >> 3);
  const int h  = bid & 127;
  const int n  = bid >> 7;
  const int p  = h & 1;
  const int nsteps = p ? 8 : 14;   // taps * (128/64)

  const int lane = tid & 63;
  const int wid  = tid >> 6;       // 0..7
  const int wr   = wid >> 2;       // w half (0..1)
  const int wc   = wid & 3;        // f quarter (0..3)
  const int l16  = lane & 15;
  const int lk   = lane >> 4;

  auto step_info = [&](int s, int& dc, int& widx, int& dr) {
    if (p == 0) {
      int ti = s >> 1; widx = ti;
      int kr, kc; even_tap(ti, dr, dc, kr, kc);
    } else {
      int q = s >> 1;
      dr = q >> 1;
      dc = (q & 1) ? 0 : -1;
      widx = (q == 0) ? 0 : (q == 1) ? 1 : (q == 2) ? 5 : 6;
    }
  };

  auto stage = [&](int s) {
    int dc, widx, dr; step_info(s, dc, widx, dr);
    const int hc = s & 1;
    const long rowbase = (long)(n * HP + (h + dr)) * WP;
    // A tile: 128 rows x 128B = 16KB, linear dest; source pixel = row + dc + 1
#pragma unroll
    for (int i = 0; i < 2; ++i) {
      const int L = i * 512 + tid;               // 0..1023
      const int row = L >> 3, slot = L & 7;
      const char* src = xpad + (rowbase + (row + dc + 1)) * 256 + hc * 128 + slot * 16;
      __builtin_amdgcn_global_load_lds(
          (const __attribute__((address_space(1))) void*)src,
          (__attribute__((address_space(3))) void*)(smem + L * 16), 16, 0, 0);
    }
    // B tile: contiguous 32KB block (both ft halves)
    const char* bsrc = wt2 + (size_t)((widx * 2 + hc) * 2) * 16384;
#pragma unroll
    for (int i = 0; i < 4; ++i) {
      const int L = i * 512 + tid;               // 0..2047
      __builtin_amdgcn_global_load_lds(
          (const __attribute__((address_space(1))) void*)(bsrc + L * 16),
          (__attribute__((address_space(3))) void*)(smem + 16384 + L * 16), 16, 0, 0);
    }
  };

  f32x4 acc[4][4] = {};

  stage(0);
  __syncthreads();

  for (int s = 0; s < nsteps; ++s) {
    int dc, widx, dr; step_info(s, dc, widx, dr);
    const char* ab = (const char*)smem;
    const char* bb = (const char*)smem + 16384;

    bf16x8 af[4][2], bfr[4][2];
#pragma unroll
    for (int m = 0; m < 4; ++m) {
      const int wl  = wr * 64 + m * 16 + l16;
      const int key = (wl + dc) & 7;               // source-column key
#pragma unroll
      for (int kk = 0; kk < 2; ++kk)
        af[m][kk] = *(const bf16x8*)(ab + wl * 128 + (((kk * 4 + lk) ^ key) * 16));
    }
#pragma unroll
    for (int fi = 0; fi < 4; ++fi) {
      const int fl = wc * 64 + fi * 16 + l16;      // 0..255
      bfr[fi][0] = *(const bf16x8*)(bb + fl * 128 + (((0 * 4 + lk) ^ (fl & 7)) * 16));
      bfr[fi][1] = *(const bf16x8*)(bb + fl * 128 + (((1 * 4 + lk) ^ (fl & 7)) * 16));
    }

#pragma unroll
    for (int m = 0; m < 4; ++m)
#pragma unroll
      for (int fi = 0; fi < 4; ++fi)
#pragma unroll
        for (int kk = 0; kk < 2; ++kk)
          acc[m][fi] = __builtin_amdgcn_mfma_f32_16x16x32_bf16(
              af[m][kk], bfr[fi][kk], acc[m][fi], 0, 0, 0);

    __syncthreads();                 // all reads of this tile done
    if (s + 1 < nsteps) stage(s + 1);
    __syncthreads();                 // staged data visible (vm drained)
  }

  // epilogue: + bias, relu, fp32 store.  D: col(f)=lane&15, row(w)=(lane>>4)*4+r
#pragma unroll
  for (int fi = 0; fi < 4; ++fi) {
    const int f = wc * 64 + fi * 16 + l16;         // 0..255
    const float bv = bias[f];
#pragma unroll
    for (int m = 0; m < 4; ++m) {
      const int w = wr * 64 + m * 16 + lk * 4;
      float* o = out + (((size_t)(n * H_ + h) * W_ + w) * F_ + f);
#pragma unroll
      for (int r = 0; r < 4; ++r) {
        float v = acc[m][fi][r] + bv;
        v = v > 0.f ? v : 0.f;
        o[(size_t)r * F_] = v;
      }
    }
  }
}

// ================= fallback (r6 kernel, proven) if ws too small =========
__device__ __forceinline__ void tap_info11(int t, int& dr, int& dc, int& kr, int& kc) {
  switch (t) {
    case 0:  dr = 0; dc = 0;  kr = 0; kc = 1; break;
    case 1:  dr = 0; dc = 1;  kr = 0; kc = 2; break;
    case 2:  dr = 1; dc = -1; kr = 1; kc = 0; break;
    case 3:  dr = 1; dc = 0;  kr = 1; kc = 1; break;
    case 4:  dr = 1; dc = 1;  kr = 1; kc = 2; break;
    case 5:  dr = 2; dc = 0;  kr = 2; kc = 1; break;
    case 6:  dr = 2; dc = 1;  kr = 2; kc = 2; break;
    case 7:  dr = 0; dc = -1; kr = 0; kc = 1; break;
    case 8:  dr = 0; dc = 0;  kr = 0; kc = 2; break;
    case 9:  dr = 1; dc = -1; kr = 2; kc = 1; break;
    default: dr = 1; dc = 0;  kr = 2; kc = 2; break;
  }
}

__global__ __launch_bounds__(256) void build_w_fb(
    const float* __restrict__ k, unsigned short* __restrict__ wt) {
  int tid = blockIdx.x * 256 + threadIdx.x;
  if (tid >= 11 * F_ * C_) return;
  int c = tid & 127;
  int f = (tid >> 7) & 255;
  int t = tid >> 15;
  int dr, dc, kr, kc;
  tap_info11(t, dr, dc, kr, kc);
  wt[tid] = (unsigned short)bf_bits(k[((kr * 3 + kc) * C_ + c) * F_ + f]);
}

__global__ __launch_bounds__(256, 3) void hconv_fb(
    const float* __restrict__ x,
    const unsigned short* __restrict__ wt,
    const float* __restrict__ bias,
    float* __restrict__ out) {
  __shared__ __align__(16) char smem[49152];
  const int tid = threadIdx.x;
  const int bid = (blockIdx.x & 7) * 1024 + (blockIdx.x >> 3);
  const int ft    = bid & 1;
  const int wtile = (bid >> 1) & 1;
  const int h     = (bid >> 2) & 127;
  const int n     = bid >> 9;
  const int f0 = ft * 128;
  const int w0 = wtile * 64;
  const int p  = h & 1;
  const int tap0   = p ? 7 : 0;
  const int nsteps = p ? 8 : 14;
  const int lane = tid & 63;
  const int wid  = tid >> 6;
  const int l16  = lane & 15;
  const int lk   = lane >> 4;
  const int awl = tid >> 2;
  const int ag2 = tid & 3;
  const int bfl   = tid >> 1;
  const int bhalf = tid & 1;
  float4 ar0, ar1, ar2, ar3;
  uint4  br0, br1, br2, br3;
  auto load_step = [&](int s) {
    const int tap = tap0 + (s >> 1);
    const int cc  = s & 1;
    int dr, dc, kr, kc;
    tap_info11(tap, dr, dc, kr, kc);
    const int hh = h + dr;
    const int wg = w0 + awl + dc;
    const bool av = (hh < H_) && (wg >= 0) && (wg < W_);
    if (av) {
      const float* ap = x + (((long)(n * H_ + hh) * W_ + wg) * C_ + cc * 64 + ag2 * 16);
      ar0 = *(const float4*)(ap);
      ar1 = *(const float4*)(ap + 4);
      ar2 = *(const float4*)(ap + 8);
      ar3 = *(const float4*)(ap + 12);
    } else {
      ar0 = ar1 = ar2 = ar3 = make_float4(0.f, 0.f, 0.f, 0.f);
    }
    const unsigned short* bp =
        wt + ((size_t)(tap * F_ + f0 + bfl) * C_ + cc * 64 + bhalf * 32);
    const uint4* bq = (const uint4*)bp;
    br0 = bq[0]; br1 = bq[1]; br2 = bq[2]; br3 = bq[3];
  };
  auto write_step = [&](int sel) {
    uint4 u0, u1;
    u0.x = pack2(ar0.x, ar0.y); u0.y = pack2(ar0.z, ar0.w);
    u0.z = pack2(ar1.x, ar1.y); u0.w = pack2(ar1.z, ar1.w);
    u1.x = pack2(ar2.x, ar2.y); u1.y = pack2(ar2.z, ar2.w);
    u1.z = pack2(ar3.x, ar3.y); u1.w = pack2(ar3.z, ar3.w);
    char* abase = (char*)smem + sel * 8192 + awl * 128;
    const int sw = awl & 7;
    *(uint4*)(abase + (((2 * ag2)     ^ sw) * 16)) = u0;
    *(uint4*)(abase + (((2 * ag2 + 1) ^ sw) * 16)) = u1;
    char* bbase = (char*)smem + 16384 + sel * 16384 + bfl * 128;
    const int sb = bfl & 7;
    *(uint4*)(bbase + (((bhalf * 4 + 0) ^ sb) * 16)) = br0;
    *(uint4*)(bbase + (((bhalf * 4 + 1) ^ sb) * 16)) = br1;
    *(uint4*)(bbase + (((bhalf * 4 + 2) ^ sb) * 16)) = br2;
    *(uint4*)(bbase + (((bhalf * 4 + 3) ^ sb) * 16)) = br3;
  };
  f32x4 acc[4][2] = {};
  load_step(0);
  write_step(0);
  load_step(1);
  __syncthreads();
  for (int s = 0; s < nsteps; ++s) {
    const int cur = s & 1;
    const char* ab = (const char*)smem + cur * 8192;
    const char* bb = (const char*)smem + 16384 + cur * 16384;
    bf16x8 af[4][2], bfr[2][2];
#pragma unroll
    for (int m = 0; m < 4; ++m)
#pragma unroll
      for (int kkk = 0; kkk < 2; ++kkk) {
        const int wl = m * 16 + l16;
        const int g  = (kkk * 4 + lk) ^ (wl & 7);
        af[m][kkk] = *(const bf16x8*)(ab + wl * 128 + g * 16);
      }
#pragma unroll
    for (int fi = 0; fi < 2; ++fi)
#pragma unroll
      for (int kkk = 0; kkk < 2; ++kkk) {
        const int fl = wid * 32 + fi * 16 + l16;
        const int g  = (kkk * 4 + lk) ^ (fl & 7);
        bfr[fi][kkk] = *(const bf16x8*)(bb + fl * 128 + g * 16);
      }
    if (s + 1 < nsteps) write_step(cur ^ 1);
    if (s + 2 < nsteps) load_step(s + 2);
#pragma unroll
    for (int m = 0; m < 4; ++m)
#pragma unroll
      for (int fi = 0; fi < 2; ++fi)
#pragma unroll
        for (int kkk = 0; kkk < 2; ++kkk)
          acc[m][fi] = __builtin_amdgcn_mfma_f32_16x16x32_bf16(
              af[m][kkk], bfr[fi][kkk], acc[m][fi], 0, 0, 0);
    __syncthreads();
  }
#pragma unroll
  for (int fi = 0; fi < 2; ++fi) {
    const int f = f0 + wid * 32 + fi * 16 + l16;
    const float bv = bias[f];
#pragma unroll
    for (int m = 0; m < 4; ++m) {
      const int w = w0 + m * 16 + lk * 4;
      float* o = out + (((size_t)(n * H_ + h) * W_ + w) * F_ + f);
#pragma unroll
      for (int r = 0; r < 4; ++r) {
        float v = acc[m][fi][r] + bv;
        v = v > 0.f ? v : 0.f;
        o[(size_t)r * F_] = v;
      }
    }
  }
}

extern "C" void kernel_launch(void* const* d_in, const int* in_sizes, int n_in,
                              void* d_out, int out_size, void* d_ws, size_t ws_size,
                              hipStream_t stream) {
  const float* x    = (const float*)d_in[0];
  const float* kern = (const float*)d_in[1];
  const float* bias = (const float*)d_in[2];
  float* out = (float*)d_out;

  const size_t XPAD_BYTES = (size_t)N_ * HP * WP * 256;   // 69,222,400
  const size_t WT2_BYTES  = (size_t)7 * 2 * 2 * 128 * 8 * 16;  // 458,752

  if (ws_size >= XPAD_BYTES + WT2_BYTES) {
    char* xpad = (char*)d_ws;
    char* wt2  = (char*)d_ws + XPAD_BYTES;
    {
      const long total = (long)N_ * HP * WP * 16;  // 4,326,400 chunks
      prep_xpad<<<(int)((total + 255) / 256), 256, 0, stream>>>(x, xpad);
    }
    prep_wt2<<<112, 256, 0, stream>>>(kern, wt2);
    hconv_mfma<<<N_ * H_, 512, 0, stream>>>(xpad, wt2, bias, out);  // 2048 blocks
  } else {
    unsigned short* wt = (unsigned short*)d_ws;   // 720,896 bytes
    build_w_fb<<<(11 * F_ * C_ + 255) / 256, 256, 0, stream>>>(kern, wt);
    hconv_fb<<<N_ * H_ * 2 * 2, 256, 0, stream>>>(x, wt, bias, out);
  }
}

// Round 11
// 170.239 us; speedup vs baseline: 1.2103x; 1.2103x over previous
//
#include <hip/hip_runtime.h>

// Hex conv:  y[h,w,f] = relu( bias[f] + sum_taps x[h+dr, w+dc, c] * K[kr,kc][c][f] )
// parity p = h&1:
//   p==0 (7 taps): (dr,dc,kr,kc) = (0,0,0,1)(0,1,0,2)(1,-1,1,0)(1,0,1,1)(1,1,1,2)(2,0,2,1)(2,1,2,2)
//   p==1 (4 taps): (0,-1,0,1)(0,0,0,2)(1,-1,2,1)(1,0,2,2)  -> weight tiles {0,1,5,6}
// x: (16,128,128,128) fp32 NHWC; K: (3,3,128,256) fp32 HWIO; bias: (256,) fp32.
// out: (16,128,128,256) fp32.
//
// Round 11: r9 geometry (128w x 128f, 4 waves, BK=64) + LDS double-buffer
// (A0@0,A1@16K,B0@32K,B1@48K = 64KB) + ONE barrier per K-step:
//   stage(s+1 -> buf^1) issued BEFORE compute of s -> load latency hidden.

#define N_  16
#define H_  128
#define W_  128
#define C_  128
#define F_  256
#define HP  130
#define WP  130

typedef short bf16x8 __attribute__((ext_vector_type(8)));  // 8 bf16 in 4 VGPRs
typedef float f32x4  __attribute__((ext_vector_type(4)));

__device__ __forceinline__ unsigned int bf_bits(float f) {
  unsigned int u = __float_as_uint(f);
  return (u + 0x7FFFu + ((u >> 16) & 1u)) >> 16;   // RNE fp32 -> bf16
}
__device__ __forceinline__ unsigned int pack2(float a, float b) {
  return bf_bits(a) | (bf_bits(b) << 16);
}

__device__ __forceinline__ void even_tap(int ti, int& dr, int& dc, int& kr, int& kc) {
  switch (ti) {
    case 0:  dr = 0; dc = 0;  kr = 0; kc = 1; break;
    case 1:  dr = 0; dc = 1;  kr = 0; kc = 2; break;
    case 2:  dr = 1; dc = -1; kr = 1; kc = 0; break;
    case 3:  dr = 1; dc = 0;  kr = 1; kc = 1; break;
    case 4:  dr = 1; dc = 1;  kr = 1; kc = 2; break;
    case 5:  dr = 2; dc = 0;  kr = 2; kc = 1; break;
    default: dr = 2; dc = 1;  kr = 2; kc = 2; break;
  }
}

// ---------- prep 1: pad + bf16-convert x, slot-swizzled by (column&7) ----------
// xpad pixel (n,hh,wp): 256B = [hc=0:128B][hc=1:128B]; each 128B = 8 slots of 16B.
// stored slot g holds channels ((g ^ ((wp-1)&7)) * 8 .. +8) + hc*64.
__global__ __launch_bounds__(256) void prep_xpad(
    const float* __restrict__ x, char* __restrict__ xpad) {
  long id = (long)blockIdx.x * 256 + threadIdx.x;     // 16B chunk id
  const long total = (long)N_ * HP * WP * 16;
  if (id >= total) return;
  const int g  = (int)(id & 7);
  const int hc = (int)((id >> 3) & 1);
  long pix = id >> 4;
  const int wp = (int)(pix % WP);
  long t = pix / WP;
  const int hh = (int)(t % HP);
  const int nn = (int)(t / HP);
  const int ww = wp - 1;
  const int key = ww & 7;
  uint4 o = make_uint4(0u, 0u, 0u, 0u);
  if (hh < H_ && ww >= 0 && ww < W_) {
    const float* s = x + (((long)(nn * H_ + hh) * W_ + ww) * C_ + hc * 64 + (g ^ key) * 8);
    float4 a = *(const float4*)s;
    float4 b = *(const float4*)(s + 4);
    o.x = pack2(a.x, a.y); o.y = pack2(a.z, a.w);
    o.z = pack2(b.x, b.y); o.w = pack2(b.z, b.w);
  }
  *(uint4*)(xpad + id * 16) = o;
}

// ---------- prep 2: weight tiles, slot-swizzled by (f&7) ----------
// wt2[ti 0..6][hc 0..1][ft 0..1] = 16KB tile: [f 0..127][slot 0..7][16B]
// stored slot g holds channels ((g ^ (f&7))*8 .. +8) + hc*64 of kernel[kr][kc][:][ft*128+f]
__global__ __launch_bounds__(256) void prep_wt2(
    const float* __restrict__ k, char* __restrict__ wt2) {
  int id = blockIdx.x * 256 + threadIdx.x;            // 16B chunk id
  if (id >= 7 * 2 * 2 * 128 * 8) return;
  const int g  = id & 7;
  const int f  = (id >> 3) & 127;
  const int ft = (id >> 10) & 1;
  const int hc = (id >> 11) & 1;
  const int ti = id >> 12;
  int dr, dc, kr, kc;
  even_tap(ti, dr, dc, kr, kc);
  const int fg = ft * 128 + f;
  const int c0 = hc * 64 + (g ^ (f & 7)) * 8;
  float v[8];
#pragma unroll
  for (int j = 0; j < 8; ++j)
    v[j] = k[((size_t)(kr * 3 + kc) * C_ + (c0 + j)) * F_ + fg];
  uint4 o;
  o.x = pack2(v[0], v[1]); o.y = pack2(v[2], v[3]);
  o.z = pack2(v[4], v[5]); o.w = pack2(v[6], v[7]);
  *(uint4*)(wt2 + (size_t)id * 16) = o;
}

// ---------- main: implicit GEMM, 128(w) x 128(f) tile, 4 waves, dbuf ----------
__global__ __launch_bounds__(256, 2) void hconv_mfma(
    const char* __restrict__ xpad,
    const char* __restrict__ wt2,
    const float* __restrict__ bias,
    float* __restrict__ out) {
  __shared__ __align__(16) char smem[65536];   // A0,A1,B0,B1 @ 16KB each

  const int tid = threadIdx.x;
  // XCD-aware bijective swizzle: grid 4096 = 8 * 512
  const int bid = (blockIdx.x & 7) * 512 + (blockIdx.x >> 3);
  const int ft = bid & 1;
  const int h  = (bid >> 1) & 127;
  const int n  = bid >> 8;
  const int p  = h & 1;
  const int nsteps = p ? 8 : 14;   // taps * (128/64)

  const int lane = tid & 63;
  const int wid  = tid >> 6;
  const int wr   = wid >> 1;       // w half (0..1)
  const int wc   = wid & 1;        // f half (0..1)
  const int l16  = lane & 15;
  const int lk   = lane >> 4;

  auto step_info = [&](int s, int& dc, int& widx, int& dr) {
    if (p == 0) {
      int ti = s >> 1; widx = ti;
      int kr, kc; even_tap(ti, dr, dc, kr, kc);
    } else {
      int q = s >> 1;
      dr = q >> 1;
      dc = (q & 1) ? 0 : -1;
      widx = (q == 0) ? 0 : (q == 1) ? 1 : (q == 2) ? 5 : 6;
    }
  };

  auto stage = [&](int s, int sel) {
    int dc, widx, dr; step_info(s, dc, widx, dr);
    const int hc = s & 1;
    const long rowbase = (long)(n * HP + (h + dr)) * WP;
    // A tile: 128 rows x 128B = 16KB, linear dest; source pixel = row + dc + 1
#pragma unroll
    for (int i = 0; i < 4; ++i) {
      const int L = i * 256 + tid;               // 0..1023
      const int row = L >> 3, slot = L & 7;
      const char* src = xpad + (rowbase + (row + dc + 1)) * 256 + hc * 128 + slot * 16;
      __builtin_amdgcn_global_load_lds(
          (const __attribute__((address_space(1))) void*)src,
          (__attribute__((address_space(3))) void*)(smem + sel * 16384 + L * 16),
          16, 0, 0);
    }
    // B tile: one contiguous 16KB block
    const char* bsrc = wt2 + (size_t)((widx * 2 + hc) * 2 + ft) * 16384;
#pragma unroll
    for (int i = 0; i < 4; ++i) {
      const int L = i * 256 + tid;
      __builtin_amdgcn_global_load_lds(
          (const __attribute__((address_space(1))) void*)(bsrc + L * 16),
          (__attribute__((address_space(3))) void*)(smem + 32768 + sel * 16384 + L * 16),
          16, 0, 0);
    }
  };

  f32x4 acc[4][4] = {};

  stage(0, 0);
  __syncthreads();

  for (int s = 0; s < nsteps; ++s) {
    const int cur = s & 1;
    // issue next-tile staging FIRST: latency hides under this step's compute
    if (s + 1 < nsteps) stage(s + 1, cur ^ 1);

    int dc, widx, dr; step_info(s, dc, widx, dr);
    const char* ab = (const char*)smem + cur * 16384;
    const char* bb = (const char*)smem + 32768 + cur * 16384;

    bf16x8 af[4][2], bfr[4][2];
#pragma unroll
    for (int m = 0; m < 4; ++m) {
      const int wl  = wr * 64 + m * 16 + l16;
      const int key = (wl + dc) & 7;               // source-column key
#pragma unroll
      for (int kk = 0; kk < 2; ++kk)
        af[m][kk] = *(const bf16x8*)(ab + wl * 128 + (((kk * 4 + lk) ^ key) * 16));
    }
#pragma unroll
    for (int fi = 0; fi < 4; ++fi) {
      const int fl = wc * 64 + fi * 16 + l16;
#pragma unroll
      for (int kk = 0; kk < 2; ++kk)
        bfr[fi][kk] = *(const bf16x8*)(bb + fl * 128 + (((kk * 4 + lk) ^ (fl & 7)) * 16));
    }

#pragma unroll
    for (int m = 0; m < 4; ++m)
#pragma unroll
      for (int fi = 0; fi < 4; ++fi)
#pragma unroll
        for (int kk = 0; kk < 2; ++kk)
          acc[m][fi] = __builtin_amdgcn_mfma_f32_16x16x32_bf16(
              af[m][kk], bfr[fi][kk], acc[m][fi], 0, 0, 0);

    // single barrier: drains this step's reads AND the (already-covered)
    // stage loads for s+1
    __syncthreads();
  }

  // epilogue: + bias, relu, fp32 store.  D: col(f)=lane&15, row(w)=(lane>>4)*4+r
#pragma unroll
  for (int fi = 0; fi < 4; ++fi) {
    const int f = ft * 128 + wc * 64 + fi * 16 + l16;
    const float bv = bias[f];
#pragma unroll
    for (int m = 0; m < 4; ++m) {
      const int w = wr * 64 + m * 16 + lk * 4;
      float* o = out + (((size_t)(n * H_ + h) * W_ + w) * F_ + f);
#pragma unroll
      for (int r = 0; r < 4; ++r) {
        float v = acc[m][fi][r] + bv;
        v = v > 0.f ? v : 0.f;
        o[(size_t)r * F_] = v;
      }
    }
  }
}

// ================= fallback (r6 kernel, proven) if ws too small =========
__device__ __forceinline__ void tap_info11(int t, int& dr, int& dc, int& kr, int& kc) {
  switch (t) {
    case 0:  dr = 0; dc = 0;  kr = 0; kc = 1; break;
    case 1:  dr = 0; dc = 1;  kr = 0; kc = 2; break;
    case 2:  dr = 1; dc = -1; kr = 1; kc = 0; break;
    case 3:  dr = 1; dc = 0;  kr = 1; kc = 1; break;
    case 4:  dr = 1; dc = 1;  kr = 1; kc = 2; break;
    case 5:  dr = 2; dc = 0;  kr = 2; kc = 1; break;
    case 6:  dr = 2; dc = 1;  kr = 2; kc = 2; break;
    case 7:  dr = 0; dc = -1; kr = 0; kc = 1; break;
    case 8:  dr = 0; dc = 0;  kr = 0; kc = 2; break;
    case 9:  dr = 1; dc = -1; kr = 2; kc = 1; break;
    default: dr = 1; dc = 0;  kr = 2; kc = 2; break;
  }
}

__global__ __launch_bounds__(256) void build_w_fb(
    const float* __restrict__ k, unsigned short* __restrict__ wt) {
  int tid = blockIdx.x * 256 + threadIdx.x;
  if (tid >= 11 * F_ * C_) return;
  int c = tid & 127;
  int f = (tid >> 7) & 255;
  int t = tid >> 15;
  int dr, dc, kr, kc;
  tap_info11(t, dr, dc, kr, kc);
  wt[tid] = (unsigned short)bf_bits(k[((kr * 3 + kc) * C_ + c) * F_ + f]);
}

__global__ __launch_bounds__(256, 3) void hconv_fb(
    const float* __restrict__ x,
    const unsigned short* __restrict__ wt,
    const float* __restrict__ bias,
    float* __restrict__ out) {
  __shared__ __align__(16) char smem[49152];
  const int tid = threadIdx.x;
  const int bid = (blockIdx.x & 7) * 1024 + (blockIdx.x >> 3);
  const int ft    = bid & 1;
  const int wtile = (bid >> 1) & 1;
  const int h     = (bid >> 2) & 127;
  const int n     = bid >> 9;
  const int f0 = ft * 128;
  const int w0 = wtile * 64;
  const int p  = h & 1;
  const int tap0   = p ? 7 : 0;
  const int nsteps = p ? 8 : 14;
  const int lane = tid & 63;
  const int wid  = tid >> 6;
  const int l16  = lane & 15;
  const int lk   = lane >> 4;
  const int awl = tid >> 2;
  const int ag2 = tid & 3;
  const int bfl   = tid >> 1;
  const int bhalf = tid & 1;
  float4 ar0, ar1, ar2, ar3;
  uint4  br0, br1, br2, br3;
  auto load_step = [&](int s) {
    const int tap = tap0 + (s >> 1);
    const int cc  = s & 1;
    int dr, dc, kr, kc;
    tap_info11(tap, dr, dc, kr, kc);
    const int hh = h + dr;
    const int wg = w0 + awl + dc;
    const bool av = (hh < H_) && (wg >= 0) && (wg < W_);
    if (av) {
      const float* ap = x + (((long)(n * H_ + hh) * W_ + wg) * C_ + cc * 64 + ag2 * 16);
      ar0 = *(const float4*)(ap);
      ar1 = *(const float4*)(ap + 4);
      ar2 = *(const float4*)(ap + 8);
      ar3 = *(const float4*)(ap + 12);
    } else {
      ar0 = ar1 = ar2 = ar3 = make_float4(0.f, 0.f, 0.f, 0.f);
    }
    const unsigned short* bp =
        wt + ((size_t)(tap * F_ + f0 + bfl) * C_ + cc * 64 + bhalf * 32);
    const uint4* bq = (const uint4*)bp;
    br0 = bq[0]; br1 = bq[1]; br2 = bq[2]; br3 = bq[3];
  };
  auto write_step = [&](int sel) {
    uint4 u0, u1;
    u0.x = pack2(ar0.x, ar0.y); u0.y = pack2(ar0.z, ar0.w);
    u0.z = pack2(ar1.x, ar1.y); u0.w = pack2(ar1.z, ar1.w);
    u1.x = pack2(ar2.x, ar2.y); u1.y = pack2(ar2.z, ar2.w);
    u1.z = pack2(ar3.x, ar3.y); u1.w = pack2(ar3.z, ar3.w);
    char* abase = (char*)smem + sel * 8192 + awl * 128;
    const int sw = awl & 7;
    *(uint4*)(abase + (((2 * ag2)     ^ sw) * 16)) = u0;
    *(uint4*)(abase + (((2 * ag2 + 1) ^ sw) * 16)) = u1;
    char* bbase = (char*)smem + 16384 + sel * 16384 + bfl * 128;
    const int sb = bfl & 7;
    *(uint4*)(bbase + (((bhalf * 4 + 0) ^ sb) * 16)) = br0;
    *(uint4*)(bbase + (((bhalf * 4 + 1) ^ sb) * 16)) = br1;
    *(uint4*)(bbase + (((bhalf * 4 + 2) ^ sb) * 16)) = br2;
    *(uint4*)(bbase + (((bhalf * 4 + 3) ^ sb) * 16)) = br3;
  };
  f32x4 acc[4][2] = {};
  load_step(0);
  write_step(0);
  load_step(1);
  __syncthreads();
  for (int s = 0; s < nsteps; ++s) {
    const int cur = s & 1;
    const char* ab = (const char*)smem + cur * 8192;
    const char* bb = (const char*)smem + 16384 + cur * 16384;
    bf16x8 af[4][2], bfr[2][2];
#pragma unroll
    for (int m = 0; m < 4; ++m)
#pragma unroll
      for (int kkk = 0; kkk < 2; ++kkk) {
        const int wl = m * 16 + l16;
        const int g  = (kkk * 4 + lk) ^ (wl & 7);
        af[m][kkk] = *(const bf16x8*)(ab + wl * 128 + g * 16);
      }
#pragma unroll
    for (int fi = 0; fi < 2; ++fi)
#pragma unroll
      for (int kkk = 0; kkk < 2; ++kkk) {
        const int fl = wid * 32 + fi * 16 + l16;
        const int g  = (kkk * 4 + lk) ^ (fl & 7);
        bfr[fi][kkk] = *(const bf16x8*)(bb + fl * 128 + g * 16);
      }
    if (s + 1 < nsteps) write_step(cur ^ 1);
    if (s + 2 < nsteps) load_step(s + 2);
#pragma unroll
    for (int m = 0; m < 4; ++m)
#pragma unroll
      for (int fi = 0; fi < 2; ++fi)
#pragma unroll
        for (int kkk = 0; kkk < 2; ++kkk)
          acc[m][fi] = __builtin_amdgcn_mfma_f32_16x16x32_bf16(
              af[m][kkk], bfr[fi][kkk], acc[m][fi], 0, 0, 0);
    __syncthreads();
  }
#pragma unroll
  for (int fi = 0; fi < 2; ++fi) {
    const int f = f0 + wid * 32 + fi * 16 + l16;
    const float bv = bias[f];
#pragma unroll
    for (int m = 0; m < 4; ++m) {
      const int w = w0 + m * 16 + lk * 4;
      float* o = out + (((size_t)(n * H_ + h) * W_ + w) * F_ + f);
#pragma unroll
      for (int r = 0; r < 4; ++r) {
        float v = acc[m][fi][r] + bv;
        v = v > 0.f ? v : 0.f;
        o[(size_t)r * F_] = v;
      }
    }
  }
}

extern "C" void kernel_launch(void* const* d_in, const int* in_sizes, int n_in,
                              void* d_out, int out_size, void* d_ws, size_t ws_size,
                              hipStream_t stream) {
  const float* x    = (const float*)d_in[0];
  const float* kern = (const float*)d_in[1];
  const float* bias = (const float*)d_in[2];
  float* out = (float*)d_out;

  const size_t XPAD_BYTES = (size_t)N_ * HP * WP * 256;   // 69,222,400
  const size_t WT2_BYTES  = (size_t)7 * 2 * 2 * 128 * 8 * 16;  // 458,752

  if (ws_size >= XPAD_BYTES + WT2_BYTES) {
    char* xpad = (char*)d_ws;
    char* wt2  = (char*)d_ws + XPAD_BYTES;
    {
      const long total = (long)N_ * HP * WP * 16;  // 4,326,400 chunks
      prep_xpad<<<(int)((total + 255) / 256), 256, 0, stream>>>(x, xpad);
    }
    prep_wt2<<<112, 256, 0, stream>>>(kern, wt2);
    hconv_mfma<<<N_ * H_ * 2, 256, 0, stream>>>(xpad, wt2, bias, out);  // 4096
  } else {
    unsigned short* wt = (unsigned short*)d_ws;   // 720,896 bytes
    build_w_fb<<<(11 * F_ * C_ + 255) / 256, 256, 0, stream>>>(kern, wt);
    hconv_fb<<<N_ * H_ * 2 * 2, 256, 0, stream>>>(x, wt, bias, out);
  }
}